// Round 7
// baseline (432.210 us; speedup 1.0000x reference)
//
#include <hip/hip_runtime.h>
#include <math.h>

#define NG  16384
#define NN  32
#define DD  128
#define RR  32
#define OO  64
#define HHH 256

// MT[r][o] = sum_h Wl[o][h] * V[h][r]  — transposed so the main kernel's
// per-lane readout column load is coalesced (lane o reads MT[r*64+o]).
__global__ void precompute_MT_kernel(const float* __restrict__ Wl,
                                     const float* __restrict__ V,
                                     float* __restrict__ MT) {
    int t = blockIdx.x * blockDim.x + threadIdx.x;   // 0..2047
    int o = t >> 5;
    int r = t & 31;
    float s = 0.f;
#pragma unroll 8
    for (int hh = 0; hh < HHH; ++hh)
        s = fmaf(Wl[o * HHH + hh], V[hh * RR + r], s);
    MT[r * OO + o] = s;
}

__device__ __forceinline__ void fma4(float4& a, float s, const float4& w) {
    a.x = fmaf(s, w.x, a.x);
    a.y = fmaf(s, w.y, a.y);
    a.z = fmaf(s, w.z, a.z);
    a.w = fmaf(s, w.w, a.w);
}

// R7: no LDS h-path at all. Lanes with the same ng read IDENTICAL h addresses
// (4n x 4r tile), so the VMEM coalescer fetches each 16B segment once per
// wave-instr (8 distinct segments, 8-way broadcast) — zero redundant HBM/L2
// traffic, zero DMA/waitcnt choreography, no barriers in the hot loop.
// W stays in LDS (R5 lesson: global-W temps in unrolled FMA loops hoist and
// spill; LDS-sourced temps don't). Spill discipline: single graph per pass
// (acc=16), depth-1 prefetch with dq+=2 and unroll 1 -> ~80 live VGPRs.
// mt[] readout column loads moved into the epilogue (not wave-lifetime).
__global__ __launch_bounds__(256, 2)
void gin_main_kernel(const float* __restrict__ hsrc,
                     const float* __restrict__ W,
                     const float* __restrict__ MT,
                     const float* __restrict__ bl,
                     float* __restrict__ out) {
    __shared__ float sW[DD * RR];   // [d][r], 16 KB, block-shared
    __shared__ float sP[4][32];     // [wave] pooled exchange

    const int tid  = threadIdx.x;
    const int lane = tid & 63;
    const int wv   = tid >> 6;
    const int rg   = lane & 7;      // r-group: r = rg*4 .. rg*4+3
    const int ng   = lane >> 3;     // n-group: n = ng, ng+8, ng+16, ng+24
    const int r0   = rg * 4;

    {   // stage W once (straight copy — same [d][r] flat layout)
        const float4* Wv  = (const float4*)W;
        float4*       sWv = (float4*)sW;
#pragma unroll
        for (int k = 0; k < 4; ++k) sWv[tid + k * 256] = Wv[tid + k * 256];
    }
    const float blv = bl[lane];
    __syncthreads();                // only block-wide barrier (sW ready)

    const int gbase = (blockIdx.x * 4 + wv) * 4;   // 4 graphs per wave
    const float* pWb = sW + r0;

#pragma unroll 1
    for (int gi = 0; gi < 4; ++gi) {
        const int g = gbase + gi;
        // lane's base row: ng. Rows covered: ng + 8k, k=0..3.
        const float* ph = hsrc + (size_t)g * (NN * DD) + ng * DD;

        float4 a0 = make_float4(0.f, 0.f, 0.f, 0.f);
        float4 a1 = a0, a2 = a0, a3 = a0;   // feat[ng+8k][r0..r0+3]

        // depth-1 prefetch double buffer over d-quads
        float4 c0 = *(const float4*)(ph + 0 * 1024 + 0);
        float4 c1 = *(const float4*)(ph + 1 * 1024 + 0);
        float4 c2 = *(const float4*)(ph + 2 * 1024 + 0);
        float4 c3 = *(const float4*)(ph + 3 * 1024 + 0);

#pragma unroll 1
        for (int dq = 0; dq < 32; dq += 2) {
            // prefetch dq+1 while computing dq
            float4 n0 = *(const float4*)(ph + 0 * 1024 + (dq + 1) * 4);
            float4 n1 = *(const float4*)(ph + 1 * 1024 + (dq + 1) * 4);
            float4 n2 = *(const float4*)(ph + 2 * 1024 + (dq + 1) * 4);
            float4 n3 = *(const float4*)(ph + 3 * 1024 + (dq + 1) * 4);
            {
                const float* pW = pWb + dq * 4 * RR;
                float4 w0 = *(const float4*)(pW + 0 * RR);
                float4 w1 = *(const float4*)(pW + 1 * RR);
                float4 w2 = *(const float4*)(pW + 2 * RR);
                float4 w3 = *(const float4*)(pW + 3 * RR);
                fma4(a0, c0.x, w0); fma4(a0, c0.y, w1); fma4(a0, c0.z, w2); fma4(a0, c0.w, w3);
                fma4(a1, c1.x, w0); fma4(a1, c1.y, w1); fma4(a1, c1.z, w2); fma4(a1, c1.w, w3);
                fma4(a2, c2.x, w0); fma4(a2, c2.y, w1); fma4(a2, c2.z, w2); fma4(a2, c2.w, w3);
                fma4(a3, c3.x, w0); fma4(a3, c3.y, w1); fma4(a3, c3.z, w2); fma4(a3, c3.w, w3);
            }
            if (dq < 30) {   // prefetch dq+2 while computing dq+1 (wave-uniform branch)
                c0 = *(const float4*)(ph + 0 * 1024 + (dq + 2) * 4);
                c1 = *(const float4*)(ph + 1 * 1024 + (dq + 2) * 4);
                c2 = *(const float4*)(ph + 2 * 1024 + (dq + 2) * 4);
                c3 = *(const float4*)(ph + 3 * 1024 + (dq + 2) * 4);
            }
            {
                const float* pW = pWb + (dq + 1) * 4 * RR;
                float4 w0 = *(const float4*)(pW + 0 * RR);
                float4 w1 = *(const float4*)(pW + 1 * RR);
                float4 w2 = *(const float4*)(pW + 2 * RR);
                float4 w3 = *(const float4*)(pW + 3 * RR);
                fma4(a0, n0.x, w0); fma4(a0, n0.y, w1); fma4(a0, n0.z, w2); fma4(a0, n0.w, w3);
                fma4(a1, n1.x, w0); fma4(a1, n1.y, w1); fma4(a1, n1.z, w2); fma4(a1, n1.w, w3);
                fma4(a2, n2.x, w0); fma4(a2, n2.y, w1); fma4(a2, n2.z, w2); fma4(a2, n2.w, w3);
                fma4(a3, n3.x, w0); fma4(a3, n3.y, w1); fma4(a3, n3.z, w2); fma4(a3, n3.w, w3);
            }
        }

        // pooled[r] = prod over 32 n: lane-local x4, butterfly across ng lanes
        float4 p;
        p.x = a0.x * a1.x * a2.x * a3.x;
        p.y = a0.y * a1.y * a2.y * a3.y;
        p.z = a0.z * a1.z * a2.z * a3.z;
        p.w = a0.w * a1.w * a2.w * a3.w;
#pragma unroll
        for (int m = 8; m <= 32; m <<= 1) {
            p.x *= __shfl_xor(p.x, m);
            p.y *= __shfl_xor(p.y, m);
            p.z *= __shfl_xor(p.z, m);
            p.w *= __shfl_xor(p.w, m);
        }
        // exchange pooled via LDS: 8 lanes write their quad, all read 32 floats
        if (ng == 0) *(float4*)(&sP[wv][r0]) = p;

        // score[o=lane] = bl + sum_r pooled[r] * MT[r][lane]
        float s = blv;
#pragma unroll
        for (int rq = 0; rq < 8; ++rq) {
            float4 pq = *(const float4*)(&sP[wv][rq * 4]);   // broadcast read
            s = fmaf(pq.x, MT[(rq * 4 + 0) * OO + lane], s);
            s = fmaf(pq.y, MT[(rq * 4 + 1) * OO + lane], s);
            s = fmaf(pq.z, MT[(rq * 4 + 2) * OO + lane], s);
            s = fmaf(pq.w, MT[(rq * 4 + 3) * OO + lane], s);
        }
        out[(size_t)g * OO + lane] = s;
    }
}

extern "C" void kernel_launch(void* const* d_in, const int* in_sizes, int n_in,
                              void* d_out, int out_size, void* d_ws, size_t ws_size,
                              hipStream_t stream) {
    const float* h  = (const float*)d_in[0];   // [16384,32,128]
    const float* W  = (const float*)d_in[1];   // [128,32]
    const float* V  = (const float*)d_in[2];   // [256,32]
    const float* Wl = (const float*)d_in[3];   // [64,256]
    const float* bl = (const float*)d_in[4];   // [64]
    float* out = (float*)d_out;                // [16384,64]
    float* MT  = (float*)d_ws;                 // [32,64] scratch (transposed M)

    precompute_MT_kernel<<<8, 256, 0, stream>>>(Wl, V, MT);
    gin_main_kernel<<<1024, 256, 0, stream>>>(h, W, MT, bl, out);
}